// Round 19
// baseline (474.066 us; speedup 1.0000x reference)
//
#include <hip/hip_runtime.h>
#include <hip/hip_bf16.h>

typedef __hip_bfloat16 bf16;
using f32x4  = __attribute__((ext_vector_type(4))) float;
using short8 = __attribute__((ext_vector_type(8))) short;
using short4v = __attribute__((ext_vector_type(4))) short;

// B=8, T=12, N=325, K=8 heads, d=64, D=512, BT=96, M=31200 (padded 31232)
#define M_ROWS   31200
#define M_PAD    31232
#define N_TOK    325
#define D_MODEL  512
#define QKV_LD   1536

#define GLOBAL_AS(p) ((const __attribute__((address_space(1))) unsigned int*)(p))
#define LDS_AS(p)    ((__attribute__((address_space(3))) unsigned int*)(p))

// ---------------------------------------------------------------------------
// dtype detection: device inputs are either f32 or bf16 (flag=1 -> f32).
__global__ void init_flag(int* flag) { if (threadIdx.x == 0) *flag = 0; }

__global__ void detect_dtype(const unsigned short* __restrict__ x, int* flag)
{
    int i = blockIdx.x * 256 + threadIdx.x;   // 64 blocks * 256 = 16384 halves
    unsigned short h = x[i];
    int e = (h >> 7) & 0xFF;
    if (e >= 135) atomicOr(flag, 1);
}

__device__ __forceinline__ float load_in(const void* p, size_t i, bool f32)
{
    return f32 ? ((const float*)p)[i] : __bfloat162float(((const bf16*)p)[i]);
}

// ---------------------------------------------------------------------------
// concat(X,STE) -> bf16 Xc[31232][1024]; rows >= 31200 zeroed.
__global__ void concat_cast(const void* __restrict__ X, const void* __restrict__ STE,
                            bf16* __restrict__ Xc, const int* __restrict__ flag)
{
    const bool f32 = (*flag != 0);
    int idx = blockIdx.x * 256 + threadIdx.x;       // M_PAD*128 tasks of 8 elems
    int r = idx >> 7, c8 = (idx & 127) << 3;
    short8 v = {0, 0, 0, 0, 0, 0, 0, 0};
    if (r < M_ROWS) {
        const void* src = (c8 < 512) ? X : STE;
        int cc = c8 & 511;
        if (f32) {
            const float* s = (const float*)src + (size_t)r * 512 + cc;
            float4 a = *(const float4*)s;
            float4 b = *(const float4*)(s + 4);
            ((bf16*)&v)[0] = __float2bfloat16(a.x); ((bf16*)&v)[1] = __float2bfloat16(a.y);
            ((bf16*)&v)[2] = __float2bfloat16(a.z); ((bf16*)&v)[3] = __float2bfloat16(a.w);
            ((bf16*)&v)[4] = __float2bfloat16(b.x); ((bf16*)&v)[5] = __float2bfloat16(b.y);
            ((bf16*)&v)[6] = __float2bfloat16(b.z); ((bf16*)&v)[7] = __float2bfloat16(b.w);
        } else {
            v = *(const short8*)((const bf16*)src + (size_t)r * 512 + cc);
        }
    }
    *(short8*)&Xc[(size_t)r * 1024 + c8] = v;
}

// ---------------------------------------------------------------------------
// batched tiled transpose of all 5 weights in ONE launch (verified round 17).
__global__ void transpose_w_all(
    const void* __restrict__ Wq, const void* __restrict__ Wk,
    const void* __restrict__ Wv, const void* __restrict__ W1,
    const void* __restrict__ W2, bf16* __restrict__ BtQKV,
    bf16* __restrict__ W1T, bf16* __restrict__ W2T,
    const int* __restrict__ flag)
{
    __shared__ float tile[32][33];
    const bool f32 = (*flag != 0);
    const int bid = blockIdx.x;
    const void* src;
    bf16* dst;
    int krows, tile_id;
    if (bid < 1536) {
        const int wsel = bid / 512;              // 0:Wq 1:Wk 2:Wv
        tile_id = bid % 512;                     // 16 x 32 tile grid
        src = (wsel == 0) ? Wq : ((wsel == 1) ? Wk : Wv);
        dst = BtQKV + (size_t)wsel * 512 * 1024;
        krows = 1024;
    } else {
        const int wsel = (bid - 1536) / 256;     // 0:W1 1:W2
        tile_id = (bid - 1536) % 256;            // 16 x 16 tile grid
        src = (wsel == 0) ? W1 : W2;
        dst = (wsel == 0) ? W1T : W2T;
        krows = 512;
    }
    const int ncols = 512;
    const int nt = (tile_id % 16) * 32;          // col tile
    const int kt = (tile_id / 16) * 32;          // row tile
    const int tx = threadIdx.x & 31, ty = threadIdx.x >> 5;   // 32 x 8
#pragma unroll
    for (int r = 0; r < 32; r += 8)
        tile[ty + r][tx] = load_in(src, (size_t)(kt + ty + r) * ncols + (nt + tx), f32);
    __syncthreads();
#pragma unroll
    for (int r = 0; r < 32; r += 8)
        dst[(size_t)(nt + ty + r) * krows + (kt + tx)] = __float2bfloat16(tile[tx][ty + r]);
}

__global__ void prep_bias(const void* __restrict__ bq, const void* __restrict__ bk,
                          const void* __restrict__ bv, const void* __restrict__ b1,
                          const void* __restrict__ b2,
                          float* __restrict__ biasQKV, float* __restrict__ b1f,
                          float* __restrict__ b2f, const int* __restrict__ flag)
{
    const bool f32 = (*flag != 0);
    int i = blockIdx.x * 256 + threadIdx.x;
    if (i < 512) {
        biasQKV[i]        = load_in(bq, i, f32);
        biasQKV[512 + i]  = load_in(bk, i, f32);
        biasQKV[1024 + i] = load_in(bv, i, f32);
        b1f[i] = load_in(b1, i, f32);
        b2f[i] = load_in(b2, i, f32);
    }
}

// ---------------------------------------------------------------------------
// 256x128-tile bf16 GEMM (verified rounds 13/15/17; all GEMMs): 512 threads,
// 8 waves (4x2 of 64x64 wave-tiles), BK=64 dual-buffer global_load_lds
// staging, n-fastest XCD-swizzled tile order. LDS 48 KB.
template<int OUTF32, int RELU>
__global__ __launch_bounds__(512) void gemm_lds256(
    const bf16* __restrict__ A, int lda,
    const bf16* __restrict__ Bt, int ldb,
    const float* __restrict__ bias, void* __restrict__ Cv,
    int Mvalid, int Kdim, int ldc, int nby)
{
    __shared__ alignas(16) bf16 As0[256 * 32];
    __shared__ alignas(16) bf16 As1[256 * 32];
    __shared__ alignas(16) bf16 Bs0[128 * 32];
    __shared__ alignas(16) bf16 Bs1[128 * 32];
    const int cpx = gridDim.x >> 3;
    const int swz = (blockIdx.x & 7) * cpx + (blockIdx.x >> 3);
    const int m0 = (swz / nby) * 256;
    const int n0 = (swz % nby) * 128;
    const int t = threadIdx.x, wave = t >> 6, lane = t & 63;
    const int wm = (wave >> 1) * 64, wn = (wave & 1) * 64;
    const int lrow = lane & 15, lk8 = (lane >> 4) * 8;
    const int srow = lane >> 2, scol = (lane & 3) << 3;
    f32x4 acc[4][4] = {};
    const int nk = Kdim >> 6;                // BK = 64

    for (int ks = 0; ks < nk; ++ks) {
        const int kk = ks << 6;
        __syncthreads();
#pragma unroll
        for (int c = 0; c < 2; ++c) {
            const int arow = wave * 32 + c * 16;
            const bf16* ga = A + (size_t)(m0 + arow + srow) * lda + kk + scol;
            __builtin_amdgcn_global_load_lds(GLOBAL_AS(ga),      LDS_AS(As0 + arow * 32), 16, 0, 0);
            __builtin_amdgcn_global_load_lds(GLOBAL_AS(ga + 32), LDS_AS(As1 + arow * 32), 16, 0, 0);
        }
        {
            const int brow = wave * 16;
            const bf16* gb = Bt + (size_t)(n0 + brow + srow) * ldb + kk + scol;
            __builtin_amdgcn_global_load_lds(GLOBAL_AS(gb),      LDS_AS(Bs0 + brow * 32), 16, 0, 0);
            __builtin_amdgcn_global_load_lds(GLOBAL_AS(gb + 32), LDS_AS(Bs1 + brow * 32), 16, 0, 0);
        }
        __syncthreads();
        short8 af[4], bfr[4];
#pragma unroll
        for (int i = 0; i < 4; ++i) {
            af[i]  = *(const short8*)&As0[(wm + i * 16 + lrow) * 32 + lk8];
            bfr[i] = *(const short8*)&Bs0[(wn + i * 16 + lrow) * 32 + lk8];
        }
#pragma unroll
        for (int i = 0; i < 4; ++i)
#pragma unroll
            for (int j = 0; j < 4; ++j)
                acc[i][j] = __builtin_amdgcn_mfma_f32_16x16x32_bf16(
                    af[i], bfr[j], acc[i][j], 0, 0, 0);
#pragma unroll
        for (int i = 0; i < 4; ++i) {
            af[i]  = *(const short8*)&As1[(wm + i * 16 + lrow) * 32 + lk8];
            bfr[i] = *(const short8*)&Bs1[(wn + i * 16 + lrow) * 32 + lk8];
        }
#pragma unroll
        for (int i = 0; i < 4; ++i)
#pragma unroll
            for (int j = 0; j < 4; ++j)
                acc[i][j] = __builtin_amdgcn_mfma_f32_16x16x32_bf16(
                    af[i], bfr[j], acc[i][j], 0, 0, 0);
    }

    const int r4 = (lane >> 4) * 4;
#pragma unroll
    for (int i = 0; i < 4; ++i) {
#pragma unroll
        for (int r = 0; r < 4; ++r) {
            int grow = m0 + wm + i * 16 + r4 + r;
            if (OUTF32 && grow >= Mvalid) continue;
#pragma unroll
            for (int j = 0; j < 4; ++j) {
                int gcol = n0 + wn + j * 16 + lrow;
                float v  = acc[i][j][r] + bias[gcol];
                if (RELU) v = fmaxf(v, 0.0f);
                if (OUTF32)
                    ((float*)Cv)[(size_t)grow * ldc + gcol] = v;
                else
                    ((bf16*)Cv)[(size_t)grow * ldc + gcol] = __float2bfloat16(v);
            }
        }
    }
}

// ---------------------------------------------------------------------------
// Attention v7: occupancy unlock. K evicted from LDS (QK B-frags read direct
// from qkv, L2-resident 42 KB/block; padded rows >=325 always masked);
// P registers halved via max-recompute: pass1 = QK MFMA for row max only,
// pass2 = recompute + single exp + pack e to bf16 (pb[22] = 44 VGPR vs 88).
// Normalization folded into attn stores (e*inv) and ctx (acc*inv). LDS
// 55.6 KB + forced <=128 VGPR (__launch_bounds__(512,4)) => 2 blocks/CU,
// 4 waves/SIMD (was 2). Balanced tile map + setprio kept from r18.
#define VT_LD  354

__device__ __forceinline__ int tile_of(int w, int it)
{
    const int m[3][8] = {
        {20, 19, 18, 17, 16, 15, 14, 13},
        { 5,  6,  7,  8,  9, 10, 11, 12},
        {-1, -1, -1,  1,  2,  3,  4,  0},
    };
    return m[it][w];
}

__global__ __launch_bounds__(512, 4) void attn_kernel(
    bf16* __restrict__ qkv, float* __restrict__ attn_out)
{
    __shared__ alignas(16) bf16 Vt[64 * VT_LD + 32];    // 45376 B
    __shared__ alignas(16) bf16 ptile[8][16 * 40];      // 10240 B
    const int t = threadIdx.x, lane = t & 63, w = t >> 6;
    const int h = blockIdx.x & 7, bt = blockIdx.x >> 3;
    const size_t rowbase = (size_t)bt * N_TOK;
    const int lrow = lane & 15, lk8 = (lane >> 4) * 8;
    const int r4 = (lane >> 4) * 4;
    const int b = bt / 12, tt2 = bt % 12;
    const size_t hb_base = (((size_t)(h * 8 + b)) * 12 + tt2) * N_TOK;
    const bf16* kbase = qkv + rowbase * QKV_LD + 512 + h * 64;

    // stage V transposed (cols 0..351, zero-padded)
    for (int task = t; task < 352 * 8; task += 512) {
        int m = task >> 3, e0 = (task & 7) << 3;
        short8 v = {0, 0, 0, 0, 0, 0, 0, 0};
        if (m < N_TOK)
            v = *(const short8*)(qkv + (rowbase + m) * QKV_LD + 1024 + h * 64 + e0);
#pragma unroll
        for (int j = 0; j < 8; ++j)
            Vt[(e0 + j) * VT_LD + m] = ((bf16*)&v)[j];
    }
    __syncthreads();   // the only block-wide barrier

    for (int it = 0; it < 3; ++it) {
        const int tile = tile_of(w, it);      // wave-uniform
        if (tile < 0) continue;
        const int r0 = tile * 16;

        int qrow = r0 + lrow; if (qrow > N_TOK - 1) qrow = N_TOK - 1;
        const bf16* qp = qkv + (rowbase + qrow) * QKV_LD + h * 64 + lk8;
        short8 qa0 = *(const short8*)(qp);
        short8 qa1 = *(const short8*)(qp + 32);

        // ---- pass 1: QK^T for row max only (scores not stored)
        float mx[4] = {-1e30f, -1e30f, -1e30f, -1e30f};
#pragma unroll
        for (int ct = 0; ct < 21; ++ct) {
            if (ct <= tile) {                 // wave-uniform branch
                const bf16* kr = kbase + (size_t)(ct * 16 + lrow) * QKV_LD;
                short8 kb0 = *(const short8*)(kr + lk8);
                short8 kb1 = *(const short8*)(kr + 32 + lk8);
                f32x4 a = {0.f, 0.f, 0.f, 0.f};
                __builtin_amdgcn_s_setprio(1);
                a = __builtin_amdgcn_mfma_f32_16x16x32_bf16(qa0, kb0, a, 0, 0, 0);
                a = __builtin_amdgcn_mfma_f32_16x16x32_bf16(qa1, kb1, a, 0, 0, 0);
                __builtin_amdgcn_s_setprio(0);
                const int c = ct * 16 + lrow;
#pragma unroll
                for (int r = 0; r < 4; ++r)
                    if (c <= r0 + r4 + r) mx[r] = fmaxf(mx[r], a[r]);
            }
        }
#pragma unroll
        for (int r = 0; r < 4; ++r) {
#pragma unroll
            for (int o = 1; o < 16; o <<= 1) mx[r] = fmaxf(mx[r], __shfl_xor(mx[r], o));
        }

        // ---- pass 2: recompute scores, exp once, pack bf16, row sums
        float sm[4] = {0.f, 0.f, 0.f, 0.f};
        short4v pb[22] = {};
#pragma unroll
        for (int ct = 0; ct < 21; ++ct) {
            if (ct <= tile) {
                const bf16* kr = kbase + (size_t)(ct * 16 + lrow) * QKV_LD;
                short8 kb0 = *(const short8*)(kr + lk8);
                short8 kb1 = *(const short8*)(kr + 32 + lk8);
                f32x4 a = {0.f, 0.f, 0.f, 0.f};
                __builtin_amdgcn_s_setprio(1);
                a = __builtin_amdgcn_mfma_f32_16x16x32_bf16(qa0, kb0, a, 0, 0, 0);
                a = __builtin_amdgcn_mfma_f32_16x16x32_bf16(qa1, kb1, a, 0, 0, 0);
                __builtin_amdgcn_s_setprio(0);
                const int c = ct * 16 + lrow;
#pragma unroll
                for (int r = 0; r < 4; ++r) {
                    float e = (c <= r0 + r4 + r)
                                  ? __expf((a[r] - mx[r]) * 0.125f) : 0.f;
                    sm[r] += e;
                    ((bf16*)&pb[ct])[r] = __float2bfloat16(e);
                }
            }
        }
        float inv[4];
#pragma unroll
        for (int r = 0; r < 4; ++r) {
#pragma unroll
            for (int o = 1; o < 16; o <<= 1) sm[r] += __shfl_xor(sm[r], o);
            inv[r] = 1.0f / sm[r];
        }

        // ---- attn stores (normalized at store; e already 0 beyond causal)
#pragma unroll
        for (int ct = 0; ct < 21; ++ct) {
            const int c = ct * 16 + lrow;
            if (c < N_TOK) {
#pragma unroll
                for (int r = 0; r < 4; ++r) {
                    const int n = r0 + r4 + r;
                    if (n < N_TOK) {
                        float v = (ct <= tile)
                            ? __bfloat162float(((bf16*)&pb[ct])[r]) * inv[r] : 0.f;
                        attn_out[(hb_base + n) * N_TOK + c] = v;
                    }
                }
            }
        }

        // ---- PV via per-wave LDS transpose chunks (unnormalized e; scale at end)
        f32x4 acc[4] = {};
        bf16* pt = &ptile[w][0];
#pragma unroll
        for (int s = 0; s < 11; ++s) {
            if (s <= (tile >> 1)) {           // wave-uniform
#pragma unroll
                for (int half = 0; half < 2; ++half) {
                    const int ct2 = 2 * s + half;
#pragma unroll
                    for (int r = 0; r < 4; ++r) {
                        bf16 v = (ct2 <= tile) ? ((bf16*)&pb[ct2])[r]
                                               : __float2bfloat16(0.f);
                        pt[(r4 + r) * 40 + half * 16 + lrow] = v;
                    }
                }
                short8 aa = *(const short8*)&pt[lrow * 40 + lk8];
                __builtin_amdgcn_s_setprio(1);
#pragma unroll
                for (int e = 0; e < 4; ++e) {
                    short8 bb = *(const short8*)&Vt[(e * 16 + lrow) * VT_LD + s * 32 + lk8];
                    acc[e] = __builtin_amdgcn_mfma_f32_16x16x32_bf16(aa, bb, acc[e], 0, 0, 0);
                }
                __builtin_amdgcn_s_setprio(0);
            }
        }

        // ---- ctx write (scaled by inv)
#pragma unroll
        for (int e = 0; e < 4; ++e) {
#pragma unroll
            for (int r = 0; r < 4; ++r) {
                const int n = r0 + r4 + r;
                if (n < N_TOK)
                    qkv[(rowbase + n) * QKV_LD + h * 64 + e * 16 + lrow] =
                        __float2bfloat16(acc[e][r] * inv[r]);
            }
        }
    }
}

// ---------------------------------------------------------------------------
extern "C" void kernel_launch(void* const* d_in, const int* in_sizes, int n_in,
                              void* d_out, int out_size, void* d_ws, size_t ws_size,
                              hipStream_t stream)
{
    const void* X   = d_in[0];
    const void* STE = d_in[1];
    const void* Wq  = d_in[2];
    const void* bq  = d_in[3];
    const void* Wk  = d_in[4];
    const void* bk  = d_in[5];
    const void* Wv  = d_in[6];
    const void* bv  = d_in[7];
    const void* W1  = d_in[8];
    const void* b1  = d_in[9];
    const void* W2  = d_in[10];
    const void* b2  = d_in[11];

    float* out0     = (float*)d_out;                              // [31200][512] f32
    float* attn_out = (float*)d_out + (size_t)M_ROWS * D_MODEL;   // [64][12][325][325] f32
    bf16*  Xc       = (bf16*)attn_out;   // scratch; overwritten by attn_kernel later

    char* ws = (char*)d_ws;
    bf16*  qkv   = (bf16*)(ws);                      // 31232*1536*2 = 95,944,704
    bf16*  BtQKV = (bf16*)(ws + 95944704);           //  3,145,728
    bf16*  W1T   = (bf16*)(ws + 99090432);           //    524,288
    bf16*  W2T   = (bf16*)(ws + 99614720);           //    524,288
    float* biasQ = (float*)(ws + 100139008);         //      6,144
    float* b1f   = (float*)(ws + 100145152);         //      2,048
    float* b2f   = (float*)(ws + 100147200);         //      2,048
    int*   flag  = (int*)(ws + 100149248);           //          4
    bf16*  hbuf  = qkv + 512;                        // FFN hidden aliases k-slice

    init_flag<<<1, 64, 0, stream>>>(flag);
    detect_dtype<<<64, 256, 0, stream>>>((const unsigned short*)X, flag);

    // all 5 weight transposes in one launch
    transpose_w_all<<<2048, 256, 0, stream>>>(Wq, Wk, Wv, W1, W2,
                                              BtQKV, W1T, W2T, flag);
    prep_bias<<<2, 256, 0, stream>>>(bq, bk, bv, b1, b2, biasQ, b1f, b2f, flag);

    // concat(X,STE) -> bf16 Xc [31232][1024]
    concat_cast<<<(M_PAD * 128) / 256, 256, 0, stream>>>(X, STE, Xc, flag);

    // QKV projection: Xc[31232,1024] @ BtQKV^T -> qkv (+bias, relu)
    gemm_lds256<0, 1><<<122 * 12, 512, 0, stream>>>(
        Xc, 1024, BtQKV, 1024, biasQ, qkv, M_PAD, 1024, QKV_LD, 12);

    // attention (ctx -> q-slice of qkv; attn -> f32 d_out region, overwrites Xc)
    attn_kernel<<<768, 512, 0, stream>>>(qkv, attn_out);

    // FFN1: relu(ctx @ W1 + b1) -> hbuf (k-slice of qkv)
    gemm_lds256<0, 1><<<122 * 4, 512, 0, stream>>>(
        qkv, QKV_LD, W1T, 512, b1f, hbuf, M_PAD, 512, QKV_LD, 4);

    // FFN2: hbuf @ W2 + b2 -> out0 (f32, guarded at M_ROWS)
    gemm_lds256<1, 0><<<122 * 4, 512, 0, stream>>>(
        hbuf, QKV_LD, W2T, 512, b2f, out0, M_ROWS, 512, D_MODEL, 4);
}

// Round 20
// 362.163 us; speedup vs baseline: 1.3090x; 1.3090x over previous
//
#include <hip/hip_runtime.h>
#include <hip/hip_bf16.h>

typedef __hip_bfloat16 bf16;
using f32x4  = __attribute__((ext_vector_type(4))) float;
using short8 = __attribute__((ext_vector_type(8))) short;

// B=8, T=12, N=325, K=8 heads, d=64, D=512, BT=96, M=31200 (padded 31232)
#define M_ROWS   31200
#define M_PAD    31232
#define N_TOK    325
#define D_MODEL  512
#define QKV_LD   1536

#define GLOBAL_AS(p) ((const __attribute__((address_space(1))) unsigned int*)(p))
#define LDS_AS(p)    ((__attribute__((address_space(3))) unsigned int*)(p))

// ---------------------------------------------------------------------------
// dtype detection: device inputs are either f32 or bf16 (flag=1 -> f32).
__global__ void init_flag(int* flag) { if (threadIdx.x == 0) *flag = 0; }

__global__ void detect_dtype(const unsigned short* __restrict__ x, int* flag)
{
    int i = blockIdx.x * 256 + threadIdx.x;   // 64 blocks * 256 = 16384 halves
    unsigned short h = x[i];
    int e = (h >> 7) & 0xFF;
    if (e >= 135) atomicOr(flag, 1);
}

__device__ __forceinline__ float load_in(const void* p, size_t i, bool f32)
{
    return f32 ? ((const float*)p)[i] : __bfloat162float(((const bf16*)p)[i]);
}

// ---------------------------------------------------------------------------
// concat(X,STE) -> bf16 Xc[31232][1024]; rows >= 31200 zeroed.
__global__ void concat_cast(const void* __restrict__ X, const void* __restrict__ STE,
                            bf16* __restrict__ Xc, const int* __restrict__ flag)
{
    const bool f32 = (*flag != 0);
    int idx = blockIdx.x * 256 + threadIdx.x;       // M_PAD*128 tasks of 8 elems
    int r = idx >> 7, c8 = (idx & 127) << 3;
    short8 v = {0, 0, 0, 0, 0, 0, 0, 0};
    if (r < M_ROWS) {
        const void* src = (c8 < 512) ? X : STE;
        int cc = c8 & 511;
        if (f32) {
            const float* s = (const float*)src + (size_t)r * 512 + cc;
            float4 a = *(const float4*)s;
            float4 b = *(const float4*)(s + 4);
            ((bf16*)&v)[0] = __float2bfloat16(a.x); ((bf16*)&v)[1] = __float2bfloat16(a.y);
            ((bf16*)&v)[2] = __float2bfloat16(a.z); ((bf16*)&v)[3] = __float2bfloat16(a.w);
            ((bf16*)&v)[4] = __float2bfloat16(b.x); ((bf16*)&v)[5] = __float2bfloat16(b.y);
            ((bf16*)&v)[6] = __float2bfloat16(b.z); ((bf16*)&v)[7] = __float2bfloat16(b.w);
        } else {
            v = *(const short8*)((const bf16*)src + (size_t)r * 512 + cc);
        }
    }
    *(short8*)&Xc[(size_t)r * 1024 + c8] = v;
}

// ---------------------------------------------------------------------------
// batched tiled transpose of all 5 weights in ONE launch (verified round 17).
__global__ void transpose_w_all(
    const void* __restrict__ Wq, const void* __restrict__ Wk,
    const void* __restrict__ Wv, const void* __restrict__ W1,
    const void* __restrict__ W2, bf16* __restrict__ BtQKV,
    bf16* __restrict__ W1T, bf16* __restrict__ W2T,
    const int* __restrict__ flag)
{
    __shared__ float tile[32][33];
    const bool f32 = (*flag != 0);
    const int bid = blockIdx.x;
    const void* src;
    bf16* dst;
    int krows, tile_id;
    if (bid < 1536) {
        const int wsel = bid / 512;              // 0:Wq 1:Wk 2:Wv
        tile_id = bid % 512;                     // 16 x 32 tile grid
        src = (wsel == 0) ? Wq : ((wsel == 1) ? Wk : Wv);
        dst = BtQKV + (size_t)wsel * 512 * 1024;
        krows = 1024;
    } else {
        const int wsel = (bid - 1536) / 256;     // 0:W1 1:W2
        tile_id = (bid - 1536) % 256;            // 16 x 16 tile grid
        src = (wsel == 0) ? W1 : W2;
        dst = (wsel == 0) ? W1T : W2T;
        krows = 512;
    }
    const int ncols = 512;
    const int nt = (tile_id % 16) * 32;          // col tile
    const int kt = (tile_id / 16) * 32;          // row tile
    const int tx = threadIdx.x & 31, ty = threadIdx.x >> 5;   // 32 x 8
#pragma unroll
    for (int r = 0; r < 32; r += 8)
        tile[ty + r][tx] = load_in(src, (size_t)(kt + ty + r) * ncols + (nt + tx), f32);
    __syncthreads();
#pragma unroll
    for (int r = 0; r < 32; r += 8)
        dst[(size_t)(nt + ty + r) * krows + (kt + tx)] = __float2bfloat16(tile[tx][ty + r]);
}

__global__ void prep_bias(const void* __restrict__ bq, const void* __restrict__ bk,
                          const void* __restrict__ bv, const void* __restrict__ b1,
                          const void* __restrict__ b2,
                          float* __restrict__ biasQKV, float* __restrict__ b1f,
                          float* __restrict__ b2f, const int* __restrict__ flag)
{
    const bool f32 = (*flag != 0);
    int i = blockIdx.x * 256 + threadIdx.x;
    if (i < 512) {
        biasQKV[i]        = load_in(bq, i, f32);
        biasQKV[512 + i]  = load_in(bk, i, f32);
        biasQKV[1024 + i] = load_in(bv, i, f32);
        b1f[i] = load_in(b1, i, f32);
        b2f[i] = load_in(b2, i, f32);
    }
}

// ---------------------------------------------------------------------------
// 256x128-tile bf16 GEMM (verified rounds 13/15/17; all GEMMs): 512 threads,
// 8 waves (4x2 of 64x64 wave-tiles), BK=64 dual-buffer global_load_lds
// staging, n-fastest XCD-swizzled tile order. LDS 48 KB.
template<int OUTF32, int RELU>
__global__ __launch_bounds__(512) void gemm_lds256(
    const bf16* __restrict__ A, int lda,
    const bf16* __restrict__ Bt, int ldb,
    const float* __restrict__ bias, void* __restrict__ Cv,
    int Mvalid, int Kdim, int ldc, int nby)
{
    __shared__ alignas(16) bf16 As0[256 * 32];
    __shared__ alignas(16) bf16 As1[256 * 32];
    __shared__ alignas(16) bf16 Bs0[128 * 32];
    __shared__ alignas(16) bf16 Bs1[128 * 32];
    const int cpx = gridDim.x >> 3;
    const int swz = (blockIdx.x & 7) * cpx + (blockIdx.x >> 3);
    const int m0 = (swz / nby) * 256;
    const int n0 = (swz % nby) * 128;
    const int t = threadIdx.x, wave = t >> 6, lane = t & 63;
    const int wm = (wave >> 1) * 64, wn = (wave & 1) * 64;
    const int lrow = lane & 15, lk8 = (lane >> 4) * 8;
    const int srow = lane >> 2, scol = (lane & 3) << 3;
    f32x4 acc[4][4] = {};
    const int nk = Kdim >> 6;                // BK = 64

    for (int ks = 0; ks < nk; ++ks) {
        const int kk = ks << 6;
        __syncthreads();
#pragma unroll
        for (int c = 0; c < 2; ++c) {
            const int arow = wave * 32 + c * 16;
            const bf16* ga = A + (size_t)(m0 + arow + srow) * lda + kk + scol;
            __builtin_amdgcn_global_load_lds(GLOBAL_AS(ga),      LDS_AS(As0 + arow * 32), 16, 0, 0);
            __builtin_amdgcn_global_load_lds(GLOBAL_AS(ga + 32), LDS_AS(As1 + arow * 32), 16, 0, 0);
        }
        {
            const int brow = wave * 16;
            const bf16* gb = Bt + (size_t)(n0 + brow + srow) * ldb + kk + scol;
            __builtin_amdgcn_global_load_lds(GLOBAL_AS(gb),      LDS_AS(Bs0 + brow * 32), 16, 0, 0);
            __builtin_amdgcn_global_load_lds(GLOBAL_AS(gb + 32), LDS_AS(Bs1 + brow * 32), 16, 0, 0);
        }
        __syncthreads();
        short8 af[4], bfr[4];
#pragma unroll
        for (int i = 0; i < 4; ++i) {
            af[i]  = *(const short8*)&As0[(wm + i * 16 + lrow) * 32 + lk8];
            bfr[i] = *(const short8*)&Bs0[(wn + i * 16 + lrow) * 32 + lk8];
        }
#pragma unroll
        for (int i = 0; i < 4; ++i)
#pragma unroll
            for (int j = 0; j < 4; ++j)
                acc[i][j] = __builtin_amdgcn_mfma_f32_16x16x32_bf16(
                    af[i], bfr[j], acc[i][j], 0, 0, 0);
#pragma unroll
        for (int i = 0; i < 4; ++i) {
            af[i]  = *(const short8*)&As1[(wm + i * 16 + lrow) * 32 + lk8];
            bfr[i] = *(const short8*)&Bs1[(wn + i * 16 + lrow) * 32 + lk8];
        }
#pragma unroll
        for (int i = 0; i < 4; ++i)
#pragma unroll
            for (int j = 0; j < 4; ++j)
                acc[i][j] = __builtin_amdgcn_mfma_f32_16x16x32_bf16(
                    af[i], bfr[j], acc[i][j], 0, 0, 0);
    }

    const int r4 = (lane >> 4) * 4;
#pragma unroll
    for (int i = 0; i < 4; ++i) {
#pragma unroll
        for (int r = 0; r < 4; ++r) {
            int grow = m0 + wm + i * 16 + r4 + r;
            if (OUTF32 && grow >= Mvalid) continue;
#pragma unroll
            for (int j = 0; j < 4; ++j) {
                int gcol = n0 + wn + j * 16 + lrow;
                float v  = acc[i][j][r] + bias[gcol];
                if (RELU) v = fmaxf(v, 0.0f);
                if (OUTF32)
                    ((float*)Cv)[(size_t)grow * ldc + gcol] = v;
                else
                    ((bf16*)Cv)[(size_t)grow * ldc + gcol] = __float2bfloat16(v);
            }
        }
    }
}

// ---------------------------------------------------------------------------
// Attention v4.2 (verified round 18, exact revert): zero main-loop barriers,
// K resident [336][72], V transposed [64][354] in LDS, in-register softmax,
// per-wave PV transpose chunk, balanced tile map (max wave cost 35 -> 32),
// s_setprio(1) around QK/PV MFMA clusters. LDS = 104 KB, 2 waves/SIMD.
#define KS_LD  72
#define VT_LD  354

__device__ __forceinline__ int tile_of(int w, int it)
{
    // coverage: it0 -> 13..20, it1 -> 5..12, it2 -> 0..4 (waves 3..7)
    // per-wave variable cost (tile+1 sums): {27,27,27,29,30,31,32,28}
    const int m[3][8] = {
        {20, 19, 18, 17, 16, 15, 14, 13},
        { 5,  6,  7,  8,  9, 10, 11, 12},
        {-1, -1, -1,  1,  2,  3,  4,  0},
    };
    return m[it][w];
}

__global__ __launch_bounds__(512) void attn_kernel(
    bf16* __restrict__ qkv, float* __restrict__ attn_out)
{
    __shared__ alignas(16) bf16 Ks[336 * KS_LD];        // 48384 B
    __shared__ alignas(16) bf16 Vt[64 * VT_LD + 32];    // 45376 B
    __shared__ alignas(16) bf16 ptile[8][16 * 40];      // 10240 B
    const int t = threadIdx.x, lane = t & 63, w = t >> 6;
    const int h = blockIdx.x & 7, bt = blockIdx.x >> 3;
    const size_t rowbase = (size_t)bt * N_TOK;
    const int lrow = lane & 15, lk8 = (lane >> 4) * 8;
    const int r4 = (lane >> 4) * 4;
    const int b = bt / 12, tt2 = bt % 12;
    const size_t hb_base = (((size_t)(h * 8 + b)) * 12 + tt2) * N_TOK;

    for (int task = t; task < 336 * 8; task += 512) {
        int m = task >> 3, e0 = (task & 7) << 3;
        short8 v = {0, 0, 0, 0, 0, 0, 0, 0};
        if (m < N_TOK)
            v = *(const short8*)(qkv + (rowbase + m) * QKV_LD + 512 + h * 64 + e0);
        *(short8*)&Ks[m * KS_LD + e0] = v;
    }
    for (int task = t; task < 352 * 8; task += 512) {
        int m = task >> 3, e0 = (task & 7) << 3;
        short8 v = {0, 0, 0, 0, 0, 0, 0, 0};
        if (m < N_TOK)
            v = *(const short8*)(qkv + (rowbase + m) * QKV_LD + 1024 + h * 64 + e0);
#pragma unroll
        for (int j = 0; j < 8; ++j)
            Vt[(e0 + j) * VT_LD + m] = ((bf16*)&v)[j];
    }
    __syncthreads();   // the only block-wide barrier

    for (int it = 0; it < 3; ++it) {
        const int tile = tile_of(w, it);      // wave-uniform
        if (tile < 0) continue;
        const int r0 = tile * 16;

        int qrow = r0 + lrow; if (qrow > N_TOK - 1) qrow = N_TOK - 1;
        const bf16* qp = qkv + (rowbase + qrow) * QKV_LD + h * 64 + lk8;
        short8 qa0 = *(const short8*)(qp);
        short8 qa1 = *(const short8*)(qp + 32);

        f32x4 f[22];
        f[21] = (f32x4){0.f, 0.f, 0.f, 0.f};
#pragma unroll
        for (int ct = 0; ct < 21; ++ct) {
            if (ct <= tile) {                 // wave-uniform branch
                f32x4 a = {0.f, 0.f, 0.f, 0.f};
                short8 kb0 = *(const short8*)&Ks[(ct * 16 + lrow) * KS_LD + lk8];
                short8 kb1 = *(const short8*)&Ks[(ct * 16 + lrow) * KS_LD + 32 + lk8];
                __builtin_amdgcn_s_setprio(1);
                a = __builtin_amdgcn_mfma_f32_16x16x32_bf16(qa0, kb0, a, 0, 0, 0);
                a = __builtin_amdgcn_mfma_f32_16x16x32_bf16(qa1, kb1, a, 0, 0, 0);
                __builtin_amdgcn_s_setprio(0);
                f[ct] = a;
            }
        }

        float mx[4] = {-1e30f, -1e30f, -1e30f, -1e30f};
        float sm[4] = {0.f, 0.f, 0.f, 0.f};
#pragma unroll
        for (int ct = 0; ct < 21; ++ct) {
            if (ct <= tile) {
                const int c = ct * 16 + lrow;
#pragma unroll
                for (int r = 0; r < 4; ++r)
                    if (c <= r0 + r4 + r) mx[r] = fmaxf(mx[r], f[ct][r]);
            }
        }
#pragma unroll
        for (int r = 0; r < 4; ++r) {
#pragma unroll
            for (int o = 1; o < 16; o <<= 1) mx[r] = fmaxf(mx[r], __shfl_xor(mx[r], o));
        }
#pragma unroll
        for (int ct = 0; ct < 21; ++ct) {
            if (ct <= tile) {
                const int c = ct * 16 + lrow;
#pragma unroll
                for (int r = 0; r < 4; ++r) {
                    float e = (c <= r0 + r4 + r)
                                  ? __expf((f[ct][r] - mx[r]) * 0.125f) : 0.f;
                    f[ct][r] = e;
                    sm[r] += e;
                }
            }
        }
#pragma unroll
        for (int r = 0; r < 4; ++r) {
#pragma unroll
            for (int o = 1; o < 16; o <<= 1) sm[r] += __shfl_xor(sm[r], o);
            sm[r] = 1.0f / sm[r];
        }
#pragma unroll
        for (int ct = 0; ct < 21; ++ct) {
            if (ct <= tile) {
#pragma unroll
                for (int r = 0; r < 4; ++r) f[ct][r] *= sm[r];
            }
        }

#pragma unroll
        for (int ct = 0; ct < 21; ++ct) {
            const int c = ct * 16 + lrow;
            if (c < N_TOK) {
#pragma unroll
                for (int r = 0; r < 4; ++r) {
                    const int n = r0 + r4 + r;
                    if (n < N_TOK) {
                        float v = (ct <= tile && c <= n) ? f[ct][r] : 0.f;
                        attn_out[(hb_base + n) * N_TOK + c] = v;
                    }
                }
            }
        }

        f32x4 acc[4] = {};
        bf16* pt = &ptile[w][0];
#pragma unroll
        for (int s = 0; s < 11; ++s) {
            if (s <= (tile >> 1)) {           // wave-uniform
#pragma unroll
                for (int half = 0; half < 2; ++half) {
                    const int ct2 = 2 * s + half;
                    const int c = ct2 * 16 + lrow;
#pragma unroll
                    for (int r = 0; r < 4; ++r) {
                        const int n = r0 + r4 + r;
                        float v = (ct2 <= tile && c <= n) ? f[ct2][r] : 0.f;
                        pt[(r4 + r) * 40 + half * 16 + lrow] = __float2bfloat16(v);
                    }
                }
                short8 aa = *(const short8*)&pt[lrow * 40 + lk8];
                __builtin_amdgcn_s_setprio(1);
#pragma unroll
                for (int e = 0; e < 4; ++e) {
                    short8 bb = *(const short8*)&Vt[(e * 16 + lrow) * VT_LD + s * 32 + lk8];
                    acc[e] = __builtin_amdgcn_mfma_f32_16x16x32_bf16(aa, bb, acc[e], 0, 0, 0);
                }
                __builtin_amdgcn_s_setprio(0);
            }
        }

#pragma unroll
        for (int e = 0; e < 4; ++e) {
#pragma unroll
            for (int r = 0; r < 4; ++r) {
                const int n = r0 + r4 + r;
                if (n < N_TOK)
                    qkv[(rowbase + n) * QKV_LD + h * 64 + e * 16 + lrow] =
                        __float2bfloat16(acc[e][r]);
            }
        }
    }
}

// ---------------------------------------------------------------------------
extern "C" void kernel_launch(void* const* d_in, const int* in_sizes, int n_in,
                              void* d_out, int out_size, void* d_ws, size_t ws_size,
                              hipStream_t stream)
{
    const void* X   = d_in[0];
    const void* STE = d_in[1];
    const void* Wq  = d_in[2];
    const void* bq  = d_in[3];
    const void* Wk  = d_in[4];
    const void* bk  = d_in[5];
    const void* Wv  = d_in[6];
    const void* bv  = d_in[7];
    const void* W1  = d_in[8];
    const void* b1  = d_in[9];
    const void* W2  = d_in[10];
    const void* b2  = d_in[11];

    float* out0     = (float*)d_out;                              // [31200][512] f32
    float* attn_out = (float*)d_out + (size_t)M_ROWS * D_MODEL;   // [64][12][325][325] f32
    bf16*  Xc       = (bf16*)attn_out;   // scratch; overwritten by attn_kernel later

    char* ws = (char*)d_ws;
    bf16*  qkv   = (bf16*)(ws);                      // 31232*1536*2 = 95,944,704
    bf16*  BtQKV = (bf16*)(ws + 95944704);           //  3,145,728
    bf16*  W1T   = (bf16*)(ws + 99090432);           //    524,288
    bf16*  W2T   = (bf16*)(ws + 99614720);           //    524,288
    float* biasQ = (float*)(ws + 100139008);         //      6,144
    float* b1f   = (float*)(ws + 100145152);         //      2,048
    float* b2f   = (float*)(ws + 100147200);         //      2,048
    int*   flag  = (int*)(ws + 100149248);           //          4
    bf16*  hbuf  = qkv + 512;                        // FFN hidden aliases k-slice

    init_flag<<<1, 64, 0, stream>>>(flag);
    detect_dtype<<<64, 256, 0, stream>>>((const unsigned short*)X, flag);

    // all 5 weight transposes in one launch
    transpose_w_all<<<2048, 256, 0, stream>>>(Wq, Wk, Wv, W1, W2,
                                              BtQKV, W1T, W2T, flag);
    prep_bias<<<2, 256, 0, stream>>>(bq, bk, bv, b1, b2, biasQ, b1f, b2f, flag);

    // concat(X,STE) -> bf16 Xc [31232][1024]
    concat_cast<<<(M_PAD * 128) / 256, 256, 0, stream>>>(X, STE, Xc, flag);

    // QKV projection: Xc[31232,1024] @ BtQKV^T -> qkv (+bias, relu)
    gemm_lds256<0, 1><<<122 * 12, 512, 0, stream>>>(
        Xc, 1024, BtQKV, 1024, biasQ, qkv, M_PAD, 1024, QKV_LD, 12);

    // attention (ctx -> q-slice of qkv; attn -> f32 d_out region, overwrites Xc)
    attn_kernel<<<768, 512, 0, stream>>>(qkv, attn_out);

    // FFN1: relu(ctx @ W1 + b1) -> hbuf (k-slice of qkv)
    gemm_lds256<0, 1><<<122 * 4, 512, 0, stream>>>(
        qkv, QKV_LD, W1T, 512, b1f, hbuf, M_PAD, 512, QKV_LD, 4);

    // FFN2: hbuf @ W2 + b2 -> out0 (f32, guarded at M_ROWS)
    gemm_lds256<1, 0><<<122 * 4, 512, 0, stream>>>(
        hbuf, QKV_LD, W2T, 512, b2f, out0, M_ROWS, 512, D_MODEL, 4);
}